// Round 2
// baseline (64.337 us; speedup 1.0000x reference)
//
#include <hip/hip_runtime.h>

typedef __attribute__((ext_vector_type(8)))  short   short8;
typedef __attribute__((ext_vector_type(4)))  unsigned uint4v;
typedef __attribute__((ext_vector_type(16))) float   f32x16;

constexpr int GRAM_BLOCKS = 256;
constexpr int MSE_BLOCKS  = 256;
constexpr int BLOCK       = 256;          // 4 waves
constexpr int SLAB_F      = 192;          // floats per (o,c) slab: 64 rows x 3
constexpr int CHUNK_SLABS = 16;
constexpr int CHUNK_F     = CHUNK_SLABS * SLAB_F;        // 3072 floats
constexpr int NSLAB       = 512 * 512;                   // 262144
constexpr int NCHUNK      = NSLAB / CHUNK_SLABS;         // 16384
constexpr int GRAM_WAVES  = GRAM_BLOCKS * (BLOCK / 64);  // 1024
constexpr int CHUNKS_PER_WAVE = NCHUNK / GRAM_WAVES;     // 16
constexpr unsigned MSE_N4 = 2097152u;                    // 8388608 floats / 4
constexpr int MSE_THREADS = MSE_BLOCKS * BLOCK;          // 65536

// ws layout (floats): [0] mse_sum ; [64 .. 64+3072) tile-encoded gram partials
// e = tile*1024 + reg*64 + lane ; tile 0 = G[0:32][0:32],
// 1 = G[0:32][32:64] (weighted x2 in finalize), 2 = G[32:64][32:64]

struct F3 { float v[3]; };                 // 12B -> global_load_dwordx3
struct Chunk { F3 a0[4], a1[4], b0[4], b1[4]; };

// pack two f32 -> one u32 of 2 bf16 (round-half-up): 2 add + 1 v_perm
__device__ __forceinline__ unsigned pk_bf16(float a, float b) {
  unsigned a2 = __builtin_bit_cast(unsigned, a) + 0x8000u;
  unsigned b2 = __builtin_bit_cast(unsigned, b) + 0x8000u;
  // bytes 0-3 from lo-arg (a2), 4-7 from hi-arg (b2): lo16=a2>>16, hi16=b2&FFFF0000
  return __builtin_amdgcn_perm(b2, a2, 0x07060302u);
}

__device__ __forceinline__ void load_chunk(const float* __restrict__ s, int laneoff,
                                           Chunk& c) {
#pragma unroll
  for (int bp = 0; bp < 4; ++bp) {
    const float* p = s + laneoff + bp * 384;   // slab pair (2bp, 2bp+1) of this half
    c.a0[bp] = *(const F3*)(p);        // slab even, row r
    c.a1[bp] = *(const F3*)(p + 96);   // slab even, row r+32
    c.b0[bp] = *(const F3*)(p + 192);  // slab odd,  row r
    c.b1[bp] = *(const F3*)(p + 288);  // slab odd,  row r+32
  }
}

__device__ __forceinline__ void mac_chunk(const Chunk& c, f32x16& a00, f32x16& a01,
                                          f32x16& a11) {
#pragma unroll
  for (int k = 0; k < 3; ++k) {
    unsigned fl[4], fh[4];
#pragma unroll
    for (int bp = 0; bp < 4; ++bp) {
      fl[bp] = pk_bf16(c.a0[bp].v[k], c.b0[bp].v[k]);
      fh[bp] = pk_bf16(c.a1[bp].v[k], c.b1[bp].v[k]);
    }
    uint4v vl = {fl[0], fl[1], fl[2], fl[3]};
    uint4v vh = {fh[0], fh[1], fh[2], fh[3]};
    short8 lo = __builtin_bit_cast(short8, vl);
    short8 hv = __builtin_bit_cast(short8, vh);
    a00 = __builtin_amdgcn_mfma_f32_32x32x16_bf16(lo, lo, a00, 0, 0, 0);
    a01 = __builtin_amdgcn_mfma_f32_32x32x16_bf16(lo, hv, a01, 0, 0, 0);
    a11 = __builtin_amdgcn_mfma_f32_32x32x16_bf16(hv, hv, a11, 0, 0, 0);
  }
}

__global__ __launch_bounds__(BLOCK, 2) void k_main(
    const float* __restrict__ X, const float* __restrict__ Y,
    const float* __restrict__ W, float* __restrict__ ws) {
  __shared__ float red[2][3072];       // 24 KiB
  const int bid = blockIdx.x;
  const int tid = threadIdx.x;

  if (bid >= GRAM_BLOCKS) {
    // ---------------- MSE partial ----------------
    const int t0 = (bid - GRAM_BLOCKS) * BLOCK + tid;
    const float4* x4 = (const float4*)X;
    const float4* y4 = (const float4*)Y;
    float acc = 0.f;
    for (unsigned i = (unsigned)t0; i < MSE_N4; i += (unsigned)MSE_THREADS) {
      float4 a = x4[i], b = y4[i];
      float d0 = a.x - b.x, d1 = a.y - b.y, d2 = a.z - b.z, d3 = a.w - b.w;
      acc += d0 * d0 + d1 * d1 + d2 * d2 + d3 * d3;
    }
#pragma unroll
    for (int o = 32; o; o >>= 1) acc += __shfl_xor(acc, o, 64);
    if ((tid & 63) == 0) atomicAdd(&ws[0], acc);
    return;
  }

  // ------------- Gram partial: direct global->VGPR, reg double-buffer -------------
  const int wave = tid >> 6;
  const int lane = tid & 63;
  const int r    = lane & 31;
  const int hi   = lane >> 5;
  const int wg   = bid * 4 + wave;
  const int laneoff = hi * 1536 + 3 * r;   // (hi*8 slabs)*192 + row r
  const float* base = W + (size_t)(wg * CHUNKS_PER_WAVE) * CHUNK_F;

  f32x16 a00{}, a01{}, a11{};
  Chunk ca, cb;
  load_chunk(base, laneoff, ca);
#pragma unroll
  for (int t = 0; t < CHUNKS_PER_WAVE; t += 2) {
    load_chunk(base + (t + 1) * CHUNK_F, laneoff, cb);
    mac_chunk(ca, a00, a01, a11);
    if (t + 2 < CHUNKS_PER_WAVE) load_chunk(base + (t + 2) * CHUNK_F, laneoff, ca);
    mac_chunk(cb, a00, a01, a11);
  }

  // ---------------- block reduce (4 waves -> 2 -> atomic) ----------------
  if (wave < 2) {
#pragma unroll
    for (int rg = 0; rg < 16; ++rg) {
      red[wave][       rg * 64 + lane] = a00[rg];
      red[wave][1024 + rg * 64 + lane] = a01[rg];
      red[wave][2048 + rg * 64 + lane] = a11[rg];
    }
  }
  __syncthreads();
  if (wave >= 2) {
    float* dst = red[wave - 2];
#pragma unroll
    for (int rg = 0; rg < 16; ++rg) {
      dst[       rg * 64 + lane] += a00[rg];
      dst[1024 + rg * 64 + lane] += a01[rg];
      dst[2048 + rg * 64 + lane] += a11[rg];
    }
  }
  __syncthreads();
  float* gram = ws + 64;
  for (int e = tid; e < 3072; e += BLOCK)
    atomicAdd(&gram[e], red[0][e] + red[1][e]);
}

__global__ __launch_bounds__(256) void k_fin(const float* __restrict__ ws,
                                             float* __restrict__ out) {
  __shared__ float g[3072];
  __shared__ float n2[64];
  __shared__ float wsum[4];
  const int tid = threadIdx.x;

  for (int e = tid; e < 3072; e += 256) g[e] = ws[64 + e];
  __syncthreads();

  // C/D layout of 32x32 mfma: col = lane&31, row = (reg&3) + 8*(reg>>2) + 4*(lane>>5)
  for (int e = tid; e < 3072; e += 256) {
    int tl = e >> 10, rg = (e >> 6) & 15, l = e & 63;
    int il = (rg & 3) + 8 * (rg >> 2) + 4 * (l >> 5);
    int jl = l & 31;
    if (tl != 1 && il == jl) n2[il + (tl == 2 ? 32 : 0)] = g[e];
  }
  __syncthreads();

  float local = 0.f;
  for (int e = tid; e < 3072; e += 256) {
    int tl = e >> 10, rg = (e >> 6) & 15, l = e & 63;
    int il = (rg & 3) + 8 * (rg >> 2) + 4 * (l >> 5);
    int jl = l & 31;
    int i, j; float wgt;
    if (tl == 0)      { i = il;      j = jl;      wgt = 1.f; }
    else if (tl == 1) { i = il;      j = jl + 32; wgt = 2.f; }  // symmetric quadrant
    else              { i = il + 32; j = jl + 32; wgt = 1.f; }
    if (i != j) {
      float sim = g[e] / sqrtf(n2[i] * n2[j]);
      if (sim > 0.2f && sim <= 1.0f) local += wgt * sim;
    }
  }
#pragma unroll
  for (int o = 32; o; o >>= 1) local += __shfl_xor(local, o, 64);
  if ((tid & 63) == 0) wsum[tid >> 6] = local;
  __syncthreads();
  if (tid == 0) {
    float reg_sum = wsum[0] + wsum[1] + wsum[2] + wsum[3];
    out[0] = ws[0] * (1.0f / 8388608.0f) + 0.0005f * reg_sum;
  }
}

extern "C" void kernel_launch(void* const* d_in, const int* in_sizes, int n_in,
                              void* d_out, int out_size, void* d_ws, size_t ws_size,
                              hipStream_t stream) {
  const float* X = (const float*)d_in[0];
  const float* Y = (const float*)d_in[1];
  const float* W = (const float*)d_in[2];
  float* ws = (float*)d_ws;

  hipMemsetAsync(d_ws, 0, (64 + 3072) * sizeof(float), stream);
  k_main<<<GRAM_BLOCKS + MSE_BLOCKS, BLOCK, 0, stream>>>(X, Y, W, ws);
  k_fin<<<1, 256, 0, stream>>>(ws, (float*)d_out);
}